// Round 1
// baseline (83.317 us; speedup 1.0000x reference)
//
#include <hip/hip_runtime.h>

// 2D Gaussian splat rasterizer.
// Strategy: tile the image 16x16 px per block (grid = H*W/256 tiles, 256 thr/blk).
// Per chunk of 1024 Gaussians: block-parallel conservative bbox-vs-tile cull,
// compact survivors (8 floats each) into LDS, then each thread (= one pixel)
// evaluates only the survivors. Expected ~66 survivors/tile vs 2048 total.

#define TILE_W 16
#define TILE_H 16
#define CHUNK  1024   // LDS: 1024 * 8 floats = 32 KB

__global__ __launch_bounds__(256)
void gsplat_kernel(const float* __restrict__ opacity,
                   const float* __restrict__ means,
                   const float* __restrict__ stds,
                   const float* __restrict__ rhos,
                   const float* __restrict__ colors,
                   const int* __restrict__ hp,
                   const int* __restrict__ wp,
                   const int* __restrict__ sp,
                   const int* __restrict__ rp,
                   float* __restrict__ out,
                   int N)
{
    __shared__ float s_rec[CHUNK * 8];
    __shared__ int s_cnt;

    const int W = wp[0];
    const float scale = (float)sp[0];
    const float ratio = (float)rp[0];
    const float cutoff2 = ratio * ratio;

    const int tiles_x = W / TILE_W;
    const int tile = blockIdx.x;
    const int tx = tile % tiles_x;
    const int ty = tile / tiles_x;

    const int tid = threadIdx.x;
    const int lx = tid & (TILE_W - 1);
    const int ly = tid / TILE_W;
    const int px = tx * TILE_W + lx;
    const int py = ty * TILE_H + ly;
    const float pxc = px + 0.5f;
    const float pyc = py + 0.5f;

    // tile pixel-center bounds (for conservative bbox cull)
    const float tx0 = tx * TILE_W + 0.5f;
    const float tx1 = tx * TILE_W + (TILE_W - 1) + 0.5f;
    const float ty0 = ty * TILE_H + 0.5f;
    const float ty1 = ty * TILE_H + (TILE_H - 1) + 0.5f;

    float accr = 0.0f, accg = 0.0f, accb = 0.0f;

    for (int base = 0; base < N; base += CHUNK) {
        __syncthreads();
        if (tid == 0) s_cnt = 0;
        __syncthreads();

        const int lim = min(N, base + CHUNK);
        for (int g = base + tid; g < lim; g += 256) {
            const float mx = means[2 * g];
            const float my = means[2 * g + 1];
            const float sx = stds[2 * g] * scale;
            const float sy = stds[2 * g + 1] * scale;
            const float ex = ratio * sx;   // ellipse bbox half-extent in x
            const float ey = ratio * sy;
            if (mx - ex <= tx1 && mx + ex >= tx0 &&
                my - ey <= ty1 && my + ey >= ty0) {
                const float rho = rhos[g];
                const float omr = 1.0f - rho * rho;
                const float ia = 1.0f / (sx * sx * omr);
                const float ic = 1.0f / (sy * sy * omr);
                const float ib = -rho / (sx * sy * omr);
                const float op = opacity[g];
                const int idx = atomicAdd(&s_cnt, 1);
                float* r = &s_rec[idx * 8];
                r[0] = mx;
                r[1] = my;
                r[2] = ia;
                r[3] = ib;
                r[4] = ic;
                r[5] = op * colors[3 * g];
                r[6] = op * colors[3 * g + 1];
                r[7] = op * colors[3 * g + 2];
            }
        }
        __syncthreads();

        const int cnt = s_cnt;
        for (int i = 0; i < cnt; ++i) {
            const float* r = &s_rec[i * 8];
            const float dx = pxc - r[0];
            const float dy = pyc - r[1];
            // same expression shape as reference: ia*dx*dx + 2*ib*dx*dy + ic*dy*dy
            const float m = r[2] * dx * dx + 2.0f * r[3] * dx * dy + r[4] * dy * dy;
            if (m <= cutoff2) {
                const float w = __expf(-0.5f * m);
                accr = fmaf(w, r[5], accr);
                accg = fmaf(w, r[6], accg);
                accb = fmaf(w, r[7], accb);
            }
        }
    }

    const int o = (py * W + px) * 3;
    out[o + 0] = accr;
    out[o + 1] = accg;
    out[o + 2] = accb;
}

extern "C" void kernel_launch(void* const* d_in, const int* in_sizes, int n_in,
                              void* d_out, int out_size, void* d_ws, size_t ws_size,
                              hipStream_t stream) {
    const float* opacity = (const float*)d_in[0];
    const float* means   = (const float*)d_in[1];
    const float* stds    = (const float*)d_in[2];
    const float* rhos    = (const float*)d_in[3];
    const float* colors  = (const float*)d_in[4];
    const int*   hp      = (const int*)d_in[5];
    const int*   wp      = (const int*)d_in[6];
    const int*   sp      = (const int*)d_in[7];
    const int*   rp      = (const int*)d_in[8];
    float* out = (float*)d_out;

    const int N = in_sizes[0];
    // H*W = out_size/3; tiles = (H/16)*(W/16) = H*W/256 (H,W divisible by 16 here)
    const int n_pixels = out_size / 3;
    const int n_tiles = n_pixels / (TILE_W * TILE_H);

    gsplat_kernel<<<n_tiles, 256, 0, stream>>>(opacity, means, stds, rhos, colors,
                                               hp, wp, sp, rp, out, N);
}

// Round 3
// 79.352 us; speedup vs baseline: 1.0500x; 1.0500x over previous
//
#include <hip/hip_runtime.h>

// 2D Gaussian splat rasterizer, v2.
// Grid = (n_tiles, NSPLIT): each block handles one 16x16-px tile and one
// 256-Gaussian chunk (1 candidate/thread). Ballot-compact survivors into LDS
// (deterministic, ascending-g order), evaluate ~8 survivors per pixel, write a
// per-split partial image into d_ws. A second kernel sums the partials.
// Rationale: 2048 blocks (8 waves/SIMD worth) vs 256 blocks (1 wave/SIMD) in
// v1 -> latency hiding for the LDS-broadcast eval loop and L2 cull loads.

__global__ __launch_bounds__(256)
void gsplat_splat(const float* __restrict__ opacity,
                  const float* __restrict__ means,
                  const float* __restrict__ stds,
                  const float* __restrict__ rhos,
                  const float* __restrict__ colors,
                  const int* __restrict__ wp,
                  const int* __restrict__ sp,
                  const int* __restrict__ rp,
                  float* __restrict__ partial,   // [S][sstride] floats
                  int N, int chunk, int sstride)
{
    __shared__ float s_rec[256 * 8];
    __shared__ int s_wcnt[4];

    const int W = wp[0];
    const float scale = (float)sp[0];
    const float ratio = (float)rp[0];
    const float cutoff2 = ratio * ratio;

    const int tiles_x = W / 16;
    const int tile = blockIdx.x;
    const int s = blockIdx.y;
    const int tx = tile % tiles_x;
    const int ty = tile / tiles_x;

    const int tid = threadIdx.x;
    const int lx = tid & 15;
    const int ly = tid >> 4;
    const int px = tx * 16 + lx;
    const int py = ty * 16 + ly;
    const float pxc = px + 0.5f;
    const float pyc = py + 0.5f;

    const float tx0 = tx * 16 + 0.5f;
    const float tx1 = tx * 16 + 15.5f;
    const float ty0 = ty * 16 + 0.5f;
    const float ty1 = ty * 16 + 15.5f;

    // ---- cull: one candidate per thread ----
    const int g = s * chunk + tid;
    bool pred = false;
    float mx = 0.f, my = 0.f, ia = 0.f, ib = 0.f, ic = 0.f;
    if (g < N && tid < chunk) {
        const float2 mm = ((const float2*)means)[g];
        const float2 ss = ((const float2*)stds)[g];
        mx = mm.x; my = mm.y;
        const float sx = ss.x * scale;
        const float sy = ss.y * scale;
        const float ex = ratio * sx;
        const float ey = ratio * sy;
        pred = (mx - ex <= tx1) & (mx + ex >= tx0) &
               (my - ey <= ty1) & (my + ey >= ty0);
        if (pred) {
            const float rho = rhos[g];
            const float omr = 1.0f - rho * rho;
            ia = 1.0f / (sx * sx * omr);
            ic = 1.0f / (sy * sy * omr);
            ib = -rho / (sx * sy * omr);
        }
    }

    // ---- deterministic ballot compaction (ascending g) ----
    const unsigned long long bal = __ballot(pred);
    const int lane = tid & 63;
    const int wv = tid >> 6;
    if (lane == 0) s_wcnt[wv] = __popcll(bal);
    __syncthreads();
    int base = 0;
#pragma unroll
    for (int i = 0; i < 4; ++i)
        if (i < wv) base += s_wcnt[i];
    const int cnt = s_wcnt[0] + s_wcnt[1] + s_wcnt[2] + s_wcnt[3];
    if (pred) {
        const int idx = base + __popcll(bal & ((1ull << lane) - 1ull));
        const float op = opacity[g];
        float* r = &s_rec[idx * 8];
        r[0] = mx;
        r[1] = my;
        r[2] = ia;
        r[3] = ib;
        r[4] = ic;
        r[5] = op * colors[3 * g];
        r[6] = op * colors[3 * g + 1];
        r[7] = op * colors[3 * g + 2];
    }
    __syncthreads();

    // ---- evaluate survivors (LDS broadcast reads) ----
    float accr = 0.0f, accg = 0.0f, accb = 0.0f;
    for (int i = 0; i < cnt; ++i) {
        const float* r = &s_rec[i * 8];
        const float dx = pxc - r[0];
        const float dy = pyc - r[1];
        const float m = r[2] * dx * dx + 2.0f * r[3] * dx * dy + r[4] * dy * dy;
        if (m <= cutoff2) {
            const float w = __expf(-0.5f * m);
            accr = fmaf(w, r[5], accr);
            accg = fmaf(w, r[6], accg);
            accb = fmaf(w, r[7], accb);
        }
    }

    float* dst = partial + (size_t)s * sstride + (py * W + px) * 3;
    dst[0] = accr;
    dst[1] = accg;
    dst[2] = accb;
}

__global__ __launch_bounds__(256)
void gsplat_reduce(const float* __restrict__ partial,
                   float* __restrict__ out,
                   int npix3, int sstride, int S)
{
    const int n4 = npix3 >> 2;           // full float4s
    const int i = blockIdx.x * 256 + threadIdx.x;
    if (i < n4) {
        const int s4 = sstride >> 2;     // sstride is 4-aligned
        const float4* p4 = (const float4*)partial;
        float4 a = p4[i];
        for (int s = 1; s < S; ++s) {
            const float4 b = p4[(size_t)s * s4 + i];
            a.x += b.x; a.y += b.y; a.z += b.z; a.w += b.w;
        }
        ((float4*)out)[i] = a;
    }
    // scalar tail (npix3 % 4 elements)
    if (blockIdx.x == 0 && threadIdx.x < (npix3 & 3)) {
        const int j = (npix3 & ~3) + threadIdx.x;
        float a = partial[j];
        for (int s = 1; s < S; ++s) a += partial[(size_t)s * sstride + j];
        out[j] = a;
    }
}

extern "C" void kernel_launch(void* const* d_in, const int* in_sizes, int n_in,
                              void* d_out, int out_size, void* d_ws, size_t ws_size,
                              hipStream_t stream) {
    const float* opacity = (const float*)d_in[0];
    const float* means   = (const float*)d_in[1];
    const float* stds    = (const float*)d_in[2];
    const float* rhos    = (const float*)d_in[3];
    const float* colors  = (const float*)d_in[4];
    const int*   wp      = (const int*)d_in[6];
    const int*   sp      = (const int*)d_in[7];
    const int*   rp      = (const int*)d_in[8];
    float* out = (float*)d_out;
    float* partial = (float*)d_ws;

    const int N = in_sizes[0];
    const int npix3 = out_size;                 // H*W*3 floats
    const int n_pixels = out_size / 3;
    const int n_tiles = n_pixels / 256;         // 16x16 tiles (H,W % 16 == 0)
    const int S = (N + 255) / 256;              // 256-Gaussian chunks
    const int chunk = (N + S - 1) / S;          // <= 256
    const int sstride = (npix3 + 3) & ~3;       // 4-aligned partial stride

    dim3 grid(n_tiles, S);
    gsplat_splat<<<grid, 256, 0, stream>>>(opacity, means, stds, rhos, colors,
                                           wp, sp, rp, partial, N, chunk, sstride);

    const int n4 = npix3 >> 2;
    const int rblocks = (n4 + 255) / 256;
    gsplat_reduce<<<rblocks, 256, 0, stream>>>(partial, out, npix3, sstride, S);
}